// Round 5
// baseline (207.639 us; speedup 1.0000x reference)
//
#include <hip/hip_runtime.h>

#define NN 50000
#define NE 600000
#define NR 500
#define DD 128
#define CAP 64   // bucket capacity per node; deg ~ Poisson(12), P(any>64) ~ 1e-25

// ---------------------------------------------------------------------------
// Workspace layout (int units):
//   OFF_CUR : NN cursors (zeroed by prep)
//   OFF_BKT : NN*CAP packed (src | typ<<16) bucket entries
//   OFF_HB  : h as bf16   (NN*DD)
//   OFF_RELB: rel as bf16 (NR*DD)
//   OFF_BP  : [W;L] bf16 MFMA B-fragments (32768 bf16)
// ---------------------------------------------------------------------------
#define OFF_CUR  0
#define OFF_BKT  (NN)
#define OFF_HB   (OFF_BKT + NN * CAP)
#define OFF_RELB (OFF_HB + NN * DD / 2)
#define OFF_BP   (OFF_RELB + NR * DD / 2)

typedef __bf16 bf16x8 __attribute__((ext_vector_type(8)));
typedef float  f32x4  __attribute__((ext_vector_type(4)));

#define HB_BLOCKS   3125   // 50000*128/8/256
#define RELB_BLOCKS 32     // 500*128/8 = 8000 threads
#define PB_BLOCKS   128    // 32768 threads
#define CZ_BLOCKS   196    // 50000 cursor zeroing
#define PREP_BLOCKS (HB_BLOCKS + RELB_BLOCKS + PB_BLOCKS + CZ_BLOCKS)

// ---------------------------------------------------------------------------
// prep: (a) h->bf16, (b) rel->bf16, (c) pack [W;L] into MFMA B fragments:
//   n = ntile*16 + (lane&15), k = kstep*32 + (lane>>4)*8 + j
//   Bp[((kstep*8 + ntile)*64 + lane)*8 + j] = bf16(B[k][n])
// (d) zero cursors.
// ---------------------------------------------------------------------------
__global__ __launch_bounds__(256) void prep(
    const float* __restrict__ h, const float* __restrict__ rel,
    const float* __restrict__ W, const float* __restrict__ L,
    __bf16* __restrict__ h_bf, __bf16* __restrict__ rel_bf,
    __bf16* __restrict__ Bp, int* __restrict__ cursor)
{
    int b = blockIdx.x;
    if (b < HB_BLOCKS) {
        int t = b * 256 + threadIdx.x;            // 8 floats per thread
        const float4* src = (const float4*)h + (size_t)t * 2;
        float4 v0 = src[0], v1 = src[1];
        bf16x8 o;
        o[0]=(__bf16)v0.x; o[1]=(__bf16)v0.y; o[2]=(__bf16)v0.z; o[3]=(__bf16)v0.w;
        o[4]=(__bf16)v1.x; o[5]=(__bf16)v1.y; o[6]=(__bf16)v1.z; o[7]=(__bf16)v1.w;
        *(bf16x8*)(h_bf + (size_t)t * 8) = o;
    } else if (b < HB_BLOCKS + RELB_BLOCKS) {
        int t = (b - HB_BLOCKS) * 256 + threadIdx.x;
        if (t < NR * DD / 8) {
            const float4* src = (const float4*)rel + (size_t)t * 2;
            float4 v0 = src[0], v1 = src[1];
            bf16x8 o;
            o[0]=(__bf16)v0.x; o[1]=(__bf16)v0.y; o[2]=(__bf16)v0.z; o[3]=(__bf16)v0.w;
            o[4]=(__bf16)v1.x; o[5]=(__bf16)v1.y; o[6]=(__bf16)v1.z; o[7]=(__bf16)v1.w;
            *(bf16x8*)(rel_bf + (size_t)t * 8) = o;
        }
    } else if (b < HB_BLOCKS + RELB_BLOCKS + PB_BLOCKS) {
        int t = (b - HB_BLOCKS - RELB_BLOCKS) * 256 + threadIdx.x;  // [0,32768)
        int lane  = (t >> 3) & 63;
        int ntile = (t >> 9) & 7;
        int kstep = t >> 12;
        int n = ntile * 16 + (lane & 15);
        int k = kstep * 32 + (lane >> 4) * 8 + (t & 7);
        float v = (k < DD) ? W[k * DD + n] : L[(k - DD) * DD + n];
        Bp[t] = (__bf16)v;
    } else {
        int t = (b - HB_BLOCKS - RELB_BLOCKS - PB_BLOCKS) * 256 + threadIdx.x;
        if (t < NN) cursor[t] = 0;
    }
}

// ---------------------------------------------------------------------------
// fill_bucket: one pass over edges, cursor atomics, packed (src|typ<<16).
// ---------------------------------------------------------------------------
__global__ __launch_bounds__(256) void fill_bucket(
    const int* __restrict__ esrc, const int* __restrict__ edst,
    const int* __restrict__ etyp, int* __restrict__ cursor,
    unsigned* __restrict__ bucket)
{
    int e = blockIdx.x * 256 + threadIdx.x;
    if (e < NE) {
        int d = edst[e];
        int pos = atomicAdd(&cursor[d], 1);
        if (pos < CAP)
            bucket[(size_t)d * CAP + pos] = (unsigned)esrc[e] | ((unsigned)etyp[e] << 16);
    }
}

// ---------------------------------------------------------------------------
// fused_gather_mfma: per 64-node block,
//   phase 1: gather agg rows (4 lanes/node, fp32 acc, *norm, ->bf16) into
//            LDS A-tile k<128; stage own h_bf rows into k>=128.
//   phase 2: 16x16x32 bf16 MFMA vs packed [W;L] fragments; relu; store.
// out written exactly once, no in-place hazard.
// ---------------------------------------------------------------------------
#define AP 264   // bf16 pitch; row = 528 B

__global__ __launch_bounds__(256) void fused_gather_mfma(
    const __bf16* __restrict__ h_bf, const __bf16* __restrict__ rel_bf,
    const float* __restrict__ norm, const int* __restrict__ cursor,
    const unsigned* __restrict__ bucket, const __bf16* __restrict__ Bp,
    float* __restrict__ out)
{
    __shared__ __bf16 As[64 * AP];   // 33792 B
    int tid = threadIdx.x;
    int row0 = blockIdx.x * 64;

    // ---- phase 1a: gather agg. group g = tid>>2 handles node row0+g;
    //      lane gl = tid&3 covers bf16 elements [gl*32, gl*32+32).
    {
        int g  = tid >> 2;
        int gl = tid & 3;
        int node = row0 + g;
        float acc[32];
#pragma unroll
        for (int j = 0; j < 32; ++j) acc[j] = 0.f;
        if (node < NN) {
            int n = cursor[node];
            n = (n < CAP) ? n : CAP;
            const unsigned* bk = bucket + (size_t)node * CAP;
            int i = 0;
            for (; i + 1 < n; i += 2) {
                unsigned p0 = bk[i], p1 = bk[i + 1];
                const __bf16* h0 = h_bf   + (size_t)(p0 & 0xFFFFu) * DD + gl * 32;
                const __bf16* r0 = rel_bf + (size_t)(p0 >> 16)     * DD + gl * 32;
                const __bf16* h1 = h_bf   + (size_t)(p1 & 0xFFFFu) * DD + gl * 32;
                const __bf16* r1 = rel_bf + (size_t)(p1 >> 16)     * DD + gl * 32;
#pragma unroll
                for (int c = 0; c < 4; ++c) {
                    bf16x8 a0 = *(const bf16x8*)(h0 + c * 8);
                    bf16x8 b0 = *(const bf16x8*)(r0 + c * 8);
                    bf16x8 a1 = *(const bf16x8*)(h1 + c * 8);
                    bf16x8 b1 = *(const bf16x8*)(r1 + c * 8);
#pragma unroll
                    for (int j = 0; j < 8; ++j)
                        acc[c * 8 + j] += ((float)a0[j] + (float)b0[j]) +
                                          ((float)a1[j] + (float)b1[j]);
                }
            }
            if (i < n) {
                unsigned p0 = bk[i];
                const __bf16* h0 = h_bf   + (size_t)(p0 & 0xFFFFu) * DD + gl * 32;
                const __bf16* r0 = rel_bf + (size_t)(p0 >> 16)     * DD + gl * 32;
#pragma unroll
                for (int c = 0; c < 4; ++c) {
                    bf16x8 a0 = *(const bf16x8*)(h0 + c * 8);
                    bf16x8 b0 = *(const bf16x8*)(r0 + c * 8);
#pragma unroll
                    for (int j = 0; j < 8; ++j)
                        acc[c * 8 + j] += (float)a0[j] + (float)b0[j];
                }
            }
            float sc = norm[node];
#pragma unroll
            for (int c = 0; c < 4; ++c) {
                bf16x8 o;
#pragma unroll
                for (int j = 0; j < 8; ++j) o[j] = (__bf16)(acc[c * 8 + j] * sc);
                *(bf16x8*)&As[g * AP + (gl * 4 + c) * 8] = o;
            }
        } else {
            bf16x8 z = (bf16x8)(__bf16)0.f;
#pragma unroll
            for (int c = 0; c < 4; ++c)
                *(bf16x8*)&As[g * AP + (gl * 4 + c) * 8] = z;
        }
    }

    // ---- phase 1b: stage own h rows into k>=128 region (disjoint from 1a)
#pragma unroll
    for (int it = 0; it < 4; ++it) {
        int idx = it * 256 + tid;       // 1024 = 64 rows x 16 chunks
        int r = idx >> 4;
        int q = idx & 15;
        int gr = row0 + r;
        bf16x8 v = (bf16x8)(__bf16)0.f;
        if (gr < NN) v = *(const bf16x8*)(h_bf + (size_t)gr * DD + q * 8);
        *(bf16x8*)&As[r * AP + DD + q * 8] = v;
    }
    __syncthreads();

    // ---- phase 2: MFMA
    int lane = tid & 63;
    int wave = tid >> 6;
    int m0 = wave * 16;
    int aoff_base = (m0 + (lane & 15)) * AP + (lane >> 4) * 8;

    f32x4 acc[8];
#pragma unroll
    for (int i = 0; i < 8; ++i) acc[i] = (f32x4)0.f;

#pragma unroll
    for (int kstep = 0; kstep < 8; ++kstep) {
        bf16x8 a = *(const bf16x8*)&As[aoff_base + kstep * 32];
        const __bf16* bbase = Bp + ((size_t)(kstep * 8) * 64 + lane) * 8;
#pragma unroll
        for (int nt = 0; nt < 8; ++nt) {
            bf16x8 b = *(const bf16x8*)(bbase + (size_t)nt * 64 * 8);
            acc[nt] = __builtin_amdgcn_mfma_f32_16x16x32_bf16(a, b, acc[nt], 0, 0, 0);
        }
    }

    // epilogue: C/D layout col=lane&15, row=(lane>>4)*4+reg
    int quad = lane >> 4;
    int col_l = lane & 15;
#pragma unroll
    for (int nt = 0; nt < 8; ++nt) {
#pragma unroll
        for (int reg = 0; reg < 4; ++reg) {
            int gr = row0 + m0 + quad * 4 + reg;
            if (gr < NN)
                out[(size_t)gr * DD + nt * 16 + col_l] = fmaxf(acc[nt][reg], 0.f);
        }
    }
}

extern "C" void kernel_launch(void* const* d_in, const int* in_sizes, int n_in,
                              void* d_out, int out_size, void* d_ws, size_t ws_size,
                              hipStream_t stream) {
    const float* h    = (const float*)d_in[0];
    const float* norm = (const float*)d_in[1];
    const float* rel  = (const float*)d_in[2];
    const float* W    = (const float*)d_in[3];
    const float* L    = (const float*)d_in[4];
    const int* esrc   = (const int*)d_in[5];
    const int* edst   = (const int*)d_in[6];
    const int* etyp   = (const int*)d_in[7];
    float* out = (float*)d_out;

    int* ws = (int*)d_ws;
    int* cursor      = ws + OFF_CUR;
    unsigned* bucket = (unsigned*)(ws + OFF_BKT);
    __bf16* h_bf     = (__bf16*)(ws + OFF_HB);
    __bf16* rel_bf   = (__bf16*)(ws + OFF_RELB);
    __bf16* Bp       = (__bf16*)(ws + OFF_BP);

    prep<<<PREP_BLOCKS, 256, 0, stream>>>(h, rel, W, L, h_bf, rel_bf, Bp, cursor);
    fill_bucket<<<(NE + 255) / 256, 256, 0, stream>>>(esrc, edst, etyp, cursor, bucket);
    fused_gather_mfma<<<(NN + 63) / 64, 256, 0, stream>>>(h_bf, rel_bf, norm, cursor,
                                                          bucket, Bp, out);
}

// Round 6
// 166.832 us; speedup vs baseline: 1.2446x; 1.2446x over previous
//
#include <hip/hip_runtime.h>

#define NN 50000
#define NE 600000
#define NR 500
#define DD 128
#define CAP 64   // bucket capacity per node; deg ~ Poisson(12), P(any>64) ~ 1e-25

// ---------------------------------------------------------------------------
// Workspace layout (int units):
//   OFF_CUR : NN cursors (zeroed by prep)
//   OFF_BKT : NN*CAP packed (src | typ<<16) bucket entries
//   OFF_HB  : h as bf16   (NN*DD)
//   OFF_RELB: rel as bf16 (NR*DD)
//   OFF_BP  : [W;L] bf16 MFMA B-fragments (32768 bf16)
// ---------------------------------------------------------------------------
#define OFF_CUR  0
#define OFF_BKT  (NN)
#define OFF_HB   (OFF_BKT + NN * CAP)
#define OFF_RELB (OFF_HB + NN * DD / 2)
#define OFF_BP   (OFF_RELB + NR * DD / 2)

typedef __bf16 bf16x8 __attribute__((ext_vector_type(8)));
typedef float  f32x4  __attribute__((ext_vector_type(4)));

#define HB_BLOCKS   3125   // 50000*128/8/256
#define RELB_BLOCKS 32     // 500*128/8 = 8000 threads
#define PB_BLOCKS   128    // 32768 threads
#define CZ_BLOCKS   196    // 50000 cursor zeroing
#define PREP_BLOCKS (HB_BLOCKS + RELB_BLOCKS + PB_BLOCKS + CZ_BLOCKS)

// ---------------------------------------------------------------------------
// prep: (a) h->bf16, (b) rel->bf16, (c) pack [W;L] into MFMA B fragments:
//   n = ntile*16 + (lane&15), k = kstep*32 + (lane>>4)*8 + j
//   Bp[((kstep*8 + ntile)*64 + lane)*8 + j] = bf16(B[k][n])
// (d) zero cursors.
// ---------------------------------------------------------------------------
__global__ __launch_bounds__(256) void prep(
    const float* __restrict__ h, const float* __restrict__ rel,
    const float* __restrict__ W, const float* __restrict__ L,
    __bf16* __restrict__ h_bf, __bf16* __restrict__ rel_bf,
    __bf16* __restrict__ Bp, int* __restrict__ cursor)
{
    int b = blockIdx.x;
    if (b < HB_BLOCKS) {
        int t = b * 256 + threadIdx.x;            // 8 floats per thread
        const float4* src = (const float4*)h + (size_t)t * 2;
        float4 v0 = src[0], v1 = src[1];
        bf16x8 o;
        o[0]=(__bf16)v0.x; o[1]=(__bf16)v0.y; o[2]=(__bf16)v0.z; o[3]=(__bf16)v0.w;
        o[4]=(__bf16)v1.x; o[5]=(__bf16)v1.y; o[6]=(__bf16)v1.z; o[7]=(__bf16)v1.w;
        *(bf16x8*)(h_bf + (size_t)t * 8) = o;
    } else if (b < HB_BLOCKS + RELB_BLOCKS) {
        int t = (b - HB_BLOCKS) * 256 + threadIdx.x;
        if (t < NR * DD / 8) {
            const float4* src = (const float4*)rel + (size_t)t * 2;
            float4 v0 = src[0], v1 = src[1];
            bf16x8 o;
            o[0]=(__bf16)v0.x; o[1]=(__bf16)v0.y; o[2]=(__bf16)v0.z; o[3]=(__bf16)v0.w;
            o[4]=(__bf16)v1.x; o[5]=(__bf16)v1.y; o[6]=(__bf16)v1.z; o[7]=(__bf16)v1.w;
            *(bf16x8*)(rel_bf + (size_t)t * 8) = o;
        }
    } else if (b < HB_BLOCKS + RELB_BLOCKS + PB_BLOCKS) {
        int t = (b - HB_BLOCKS - RELB_BLOCKS) * 256 + threadIdx.x;  // [0,32768)
        int lane  = (t >> 3) & 63;
        int ntile = (t >> 9) & 7;
        int kstep = t >> 12;
        int n = ntile * 16 + (lane & 15);
        int k = kstep * 32 + (lane >> 4) * 8 + (t & 7);
        float v = (k < DD) ? W[k * DD + n] : L[(k - DD) * DD + n];
        Bp[t] = (__bf16)v;
    } else {
        int t = (b - HB_BLOCKS - RELB_BLOCKS - PB_BLOCKS) * 256 + threadIdx.x;
        if (t < NN) cursor[t] = 0;
    }
}

// ---------------------------------------------------------------------------
// fill_bucket: one pass over edges, cursor atomics, packed (src|typ<<16).
// ---------------------------------------------------------------------------
__global__ __launch_bounds__(256) void fill_bucket(
    const int* __restrict__ esrc, const int* __restrict__ edst,
    const int* __restrict__ etyp, int* __restrict__ cursor,
    unsigned* __restrict__ bucket)
{
    int e = blockIdx.x * 256 + threadIdx.x;
    if (e < NE) {
        int d = edst[e];
        int pos = atomicAdd(&cursor[d], 1);
        if (pos < CAP)
            bucket[(size_t)d * CAP + pos] = (unsigned)esrc[e] | ((unsigned)etyp[e] << 16);
    }
}

// ---------------------------------------------------------------------------
// fused_gather_mfma: 16 nodes per block (grid = NN/16 = 3125, exact).
//   phase 1: gather (16 lanes/node, bf16x8/lane, fp32 acc, *norm -> bf16 LDS)
//            + stage own h rows into k>=128 half of the A-tile.
//   phase 2: all 4 waves share the 16 A-rows; wave w computes n-tiles
//            {2w, 2w+1}: 8 ksteps x 2 = 16 MFMA/wave. relu, store.
// High block count keeps the latency-bound gather phase saturated (fixes
// R5's 23% occupancy), while keeping the 3-dispatch pipeline.
// ---------------------------------------------------------------------------
#define AP 264   // bf16 pitch; row = 528 B

__global__ __launch_bounds__(256) void fused_gather_mfma(
    const __bf16* __restrict__ h_bf, const __bf16* __restrict__ rel_bf,
    const float* __restrict__ norm, const int* __restrict__ cursor,
    const unsigned* __restrict__ bucket, const __bf16* __restrict__ Bp,
    float* __restrict__ out)
{
    __shared__ __bf16 As[16 * AP];   // 8448 B
    int tid = threadIdx.x;
    int row0 = blockIdx.x * 16;
    int g    = tid >> 4;             // node group 0..15
    int gl   = tid & 15;             // lane within node: bf16 [gl*8, gl*8+8)
    int node = row0 + g;             // always < NN (exact grid)

    // ---- phase 1: gather agg row (fp32 acc), 4-edge unroll for MLP
    int n = cursor[node];
    n = (n < CAP) ? n : CAP;
    const unsigned* bk = bucket + (size_t)node * CAP;
    float acc[8];
#pragma unroll
    for (int j = 0; j < 8; ++j) acc[j] = 0.f;
    int i = 0;
    for (; i + 3 < n; i += 4) {
        unsigned p0 = bk[i], p1 = bk[i+1], p2 = bk[i+2], p3 = bk[i+3];
        bf16x8 a0 = *(const bf16x8*)(h_bf   + (size_t)(p0 & 0xFFFFu) * DD + gl * 8);
        bf16x8 b0 = *(const bf16x8*)(rel_bf + (size_t)(p0 >> 16)     * DD + gl * 8);
        bf16x8 a1 = *(const bf16x8*)(h_bf   + (size_t)(p1 & 0xFFFFu) * DD + gl * 8);
        bf16x8 b1 = *(const bf16x8*)(rel_bf + (size_t)(p1 >> 16)     * DD + gl * 8);
        bf16x8 a2 = *(const bf16x8*)(h_bf   + (size_t)(p2 & 0xFFFFu) * DD + gl * 8);
        bf16x8 b2 = *(const bf16x8*)(rel_bf + (size_t)(p2 >> 16)     * DD + gl * 8);
        bf16x8 a3 = *(const bf16x8*)(h_bf   + (size_t)(p3 & 0xFFFFu) * DD + gl * 8);
        bf16x8 b3 = *(const bf16x8*)(rel_bf + (size_t)(p3 >> 16)     * DD + gl * 8);
#pragma unroll
        for (int j = 0; j < 8; ++j)
            acc[j] += (((float)a0[j] + (float)b0[j]) + ((float)a1[j] + (float)b1[j]))
                    + (((float)a2[j] + (float)b2[j]) + ((float)a3[j] + (float)b3[j]));
    }
    for (; i < n; ++i) {
        unsigned p0 = bk[i];
        bf16x8 a0 = *(const bf16x8*)(h_bf   + (size_t)(p0 & 0xFFFFu) * DD + gl * 8);
        bf16x8 b0 = *(const bf16x8*)(rel_bf + (size_t)(p0 >> 16)     * DD + gl * 8);
#pragma unroll
        for (int j = 0; j < 8; ++j) acc[j] += (float)a0[j] + (float)b0[j];
    }
    float sc = norm[node];
    bf16x8 o;
#pragma unroll
    for (int j = 0; j < 8; ++j) o[j] = (__bf16)(acc[j] * sc);
    *(bf16x8*)&As[g * AP + gl * 8] = o;
    // stage own h row into k>=128 half (one bf16x8 per thread)
    *(bf16x8*)&As[g * AP + DD + gl * 8] =
        *(const bf16x8*)(h_bf + (size_t)node * DD + gl * 8);
    __syncthreads();

    // ---- phase 2: MFMA. wave w -> n-tiles 2w, 2w+1 over shared 16 A-rows.
    int lane = tid & 63;
    int wave = tid >> 6;
    int aoff = (lane & 15) * AP + (lane >> 4) * 8;

    f32x4 c0 = (f32x4)0.f, c1 = (f32x4)0.f;
    int nt0 = wave * 2;
#pragma unroll
    for (int kstep = 0; kstep < 8; ++kstep) {
        bf16x8 a = *(const bf16x8*)&As[aoff + kstep * 32];
        const __bf16* bbase = Bp + ((size_t)(kstep * 8 + nt0) * 64 + lane) * 8;
        bf16x8 b0 = *(const bf16x8*)bbase;
        bf16x8 b1 = *(const bf16x8*)(bbase + 64 * 8);
        c0 = __builtin_amdgcn_mfma_f32_16x16x32_bf16(a, b0, c0, 0, 0, 0);
        c1 = __builtin_amdgcn_mfma_f32_16x16x32_bf16(a, b1, c1, 0, 0, 0);
    }

    // epilogue: C/D layout col=lane&15, row=(lane>>4)*4+reg; rows all < NN
    int quad = lane >> 4;
    int col  = lane & 15;
#pragma unroll
    for (int reg = 0; reg < 4; ++reg) {
        float* op = out + (size_t)(row0 + quad * 4 + reg) * DD + col;
        op[nt0 * 16]       = fmaxf(c0[reg], 0.f);
        op[(nt0 + 1) * 16] = fmaxf(c1[reg], 0.f);
    }
}

extern "C" void kernel_launch(void* const* d_in, const int* in_sizes, int n_in,
                              void* d_out, int out_size, void* d_ws, size_t ws_size,
                              hipStream_t stream) {
    const float* h    = (const float*)d_in[0];
    const float* norm = (const float*)d_in[1];
    const float* rel  = (const float*)d_in[2];
    const float* W    = (const float*)d_in[3];
    const float* L    = (const float*)d_in[4];
    const int* esrc   = (const int*)d_in[5];
    const int* edst   = (const int*)d_in[6];
    const int* etyp   = (const int*)d_in[7];
    float* out = (float*)d_out;

    int* ws = (int*)d_ws;
    int* cursor      = ws + OFF_CUR;
    unsigned* bucket = (unsigned*)(ws + OFF_BKT);
    __bf16* h_bf     = (__bf16*)(ws + OFF_HB);
    __bf16* rel_bf   = (__bf16*)(ws + OFF_RELB);
    __bf16* Bp       = (__bf16*)(ws + OFF_BP);

    prep<<<PREP_BLOCKS, 256, 0, stream>>>(h, rel, W, L, h_bf, rel_bf, Bp, cursor);
    fill_bucket<<<(NE + 255) / 256, 256, 0, stream>>>(esrc, edst, etyp, cursor, bucket);
    fused_gather_mfma<<<NN / 16, 256, 0, stream>>>(h_bf, rel_bf, norm, cursor,
                                                   bucket, Bp, out);
}

// Round 7
// 164.925 us; speedup vs baseline: 1.2590x; 1.0116x over previous
//
#include <hip/hip_runtime.h>

#define NN 50000
#define NE 600000
#define NR 500
#define DD 128
#define CAP 64   // bucket capacity per node; deg ~ Poisson(12), P(any>64) ~ 1e-25

// ---------------------------------------------------------------------------
// Workspace layout (int units):
//   OFF_CUR : NN cursors (zeroed by prep)
//   OFF_BKT : NN*CAP packed (src | typ<<16) bucket entries
//   OFF_HB  : h as bf16   (NN*DD)
//   OFF_RELB: rel as bf16 (NR*DD)
//   OFF_BP  : [W;L] bf16 MFMA B-fragments (32768 bf16)
// ---------------------------------------------------------------------------
#define OFF_CUR  0
#define OFF_BKT  (NN)
#define OFF_HB   (OFF_BKT + NN * CAP)
#define OFF_RELB (OFF_HB + NN * DD / 2)
#define OFF_BP   (OFF_RELB + NR * DD / 2)

typedef __bf16 bf16x8 __attribute__((ext_vector_type(8)));
typedef float  f32x4  __attribute__((ext_vector_type(4)));

#define HB_BLOCKS   3125   // 50000*128/8/256
#define RELB_BLOCKS 32     // 500*128/8 = 8000 threads
#define PB_BLOCKS   128    // 32768 threads
#define CZ_BLOCKS   196    // 50000 cursor zeroing
#define PREP_BLOCKS (HB_BLOCKS + RELB_BLOCKS + PB_BLOCKS + CZ_BLOCKS)

// ---------------------------------------------------------------------------
// prep: (a) h->bf16, (b) rel->bf16, (c) pack [W;L] into MFMA B fragments:
//   n = ntile*16 + (lane&15), k = kstep*32 + (lane>>4)*8 + j
//   Bp[((kstep*8 + ntile)*64 + lane)*8 + j] = bf16(B[k][n])
// (d) zero cursors.
// ---------------------------------------------------------------------------
__global__ __launch_bounds__(256) void prep(
    const float* __restrict__ h, const float* __restrict__ rel,
    const float* __restrict__ W, const float* __restrict__ L,
    __bf16* __restrict__ h_bf, __bf16* __restrict__ rel_bf,
    __bf16* __restrict__ Bp, int* __restrict__ cursor)
{
    int b = blockIdx.x;
    if (b < HB_BLOCKS) {
        int t = b * 256 + threadIdx.x;            // 8 floats per thread
        const float4* src = (const float4*)h + (size_t)t * 2;
        float4 v0 = src[0], v1 = src[1];
        bf16x8 o;
        o[0]=(__bf16)v0.x; o[1]=(__bf16)v0.y; o[2]=(__bf16)v0.z; o[3]=(__bf16)v0.w;
        o[4]=(__bf16)v1.x; o[5]=(__bf16)v1.y; o[6]=(__bf16)v1.z; o[7]=(__bf16)v1.w;
        *(bf16x8*)(h_bf + (size_t)t * 8) = o;
    } else if (b < HB_BLOCKS + RELB_BLOCKS) {
        int t = (b - HB_BLOCKS) * 256 + threadIdx.x;
        if (t < NR * DD / 8) {
            const float4* src = (const float4*)rel + (size_t)t * 2;
            float4 v0 = src[0], v1 = src[1];
            bf16x8 o;
            o[0]=(__bf16)v0.x; o[1]=(__bf16)v0.y; o[2]=(__bf16)v0.z; o[3]=(__bf16)v0.w;
            o[4]=(__bf16)v1.x; o[5]=(__bf16)v1.y; o[6]=(__bf16)v1.z; o[7]=(__bf16)v1.w;
            *(bf16x8*)(rel_bf + (size_t)t * 8) = o;
        }
    } else if (b < HB_BLOCKS + RELB_BLOCKS + PB_BLOCKS) {
        int t = (b - HB_BLOCKS - RELB_BLOCKS) * 256 + threadIdx.x;  // [0,32768)
        int lane  = (t >> 3) & 63;
        int ntile = (t >> 9) & 7;
        int kstep = t >> 12;
        int n = ntile * 16 + (lane & 15);
        int k = kstep * 32 + (lane >> 4) * 8 + (t & 7);
        float v = (k < DD) ? W[k * DD + n] : L[(k - DD) * DD + n];
        Bp[t] = (__bf16)v;
    } else {
        int t = (b - HB_BLOCKS - RELB_BLOCKS - PB_BLOCKS) * 256 + threadIdx.x;
        if (t < NN) cursor[t] = 0;
    }
}

// ---------------------------------------------------------------------------
// fill_bucket: 4 edges per thread via int4 loads; cursor atomics; packed
// (src|typ<<16) scatter into buckets.
// ---------------------------------------------------------------------------
__global__ __launch_bounds__(256) void fill_bucket(
    const int* __restrict__ esrc, const int* __restrict__ edst,
    const int* __restrict__ etyp, int* __restrict__ cursor,
    unsigned* __restrict__ bucket)
{
    int e4 = blockIdx.x * 256 + threadIdx.x;   // NE/4 = 150000 threads
    if (e4 * 4 >= NE) return;
    int4 s = ((const int4*)esrc)[e4];
    int4 d = ((const int4*)edst)[e4];
    int4 t = ((const int4*)etyp)[e4];
    {
        int pos = atomicAdd(&cursor[d.x], 1);
        if (pos < CAP) bucket[(size_t)d.x * CAP + pos] = (unsigned)s.x | ((unsigned)t.x << 16);
    }
    {
        int pos = atomicAdd(&cursor[d.y], 1);
        if (pos < CAP) bucket[(size_t)d.y * CAP + pos] = (unsigned)s.y | ((unsigned)t.y << 16);
    }
    {
        int pos = atomicAdd(&cursor[d.z], 1);
        if (pos < CAP) bucket[(size_t)d.z * CAP + pos] = (unsigned)s.z | ((unsigned)t.z << 16);
    }
    {
        int pos = atomicAdd(&cursor[d.w], 1);
        if (pos < CAP) bucket[(size_t)d.w * CAP + pos] = (unsigned)s.w | ((unsigned)t.w << 16);
    }
}

// ---------------------------------------------------------------------------
// fused_gather_mfma: 16 nodes per block (grid = NN/16 = 3125, exact).
//   phase 1: gather (16 lanes/node, bf16x8/lane, fp32 acc, *norm -> bf16 LDS)
//            with 8-edge unroll (16 outstanding loads/lane); own h row + norm
//            hoisted before the loop; stage h into k>=128 half of A-tile.
//   phase 2: all 4 waves share the 16 A-rows; wave w computes n-tiles
//            {2w, 2w+1}: 8 ksteps x 2 = 16 MFMA/wave. relu, store.
// ---------------------------------------------------------------------------
#define AP 264   // bf16 pitch; row = 528 B

__global__ __launch_bounds__(256) void fused_gather_mfma(
    const __bf16* __restrict__ h_bf, const __bf16* __restrict__ rel_bf,
    const float* __restrict__ norm, const int* __restrict__ cursor,
    const unsigned* __restrict__ bucket, const __bf16* __restrict__ Bp,
    float* __restrict__ out)
{
    __shared__ __bf16 As[16 * AP];   // 8448 B
    int tid = threadIdx.x;
    int row0 = blockIdx.x * 16;
    int g    = tid >> 4;             // node group 0..15
    int gl   = tid & 15;             // lane within node: bf16 [gl*8, gl*8+8)
    int node = row0 + g;             // always < NN (exact grid)

    // hoisted independent loads: own h row (for k>=128 stage), norm, degree
    bf16x8 own_h = *(const bf16x8*)(h_bf + (size_t)node * DD + gl * 8);
    float sc = norm[node];
    int n = cursor[node];
    n = (n < CAP) ? n : CAP;
    const unsigned* bk = bucket + (size_t)node * CAP;

    float acc[8];
#pragma unroll
    for (int j = 0; j < 8; ++j) acc[j] = 0.f;

    int i = 0;
    for (; i + 7 < n; i += 8) {      // 8-edge unroll: 16 loads in flight/lane
        bf16x8 a[8], r[8];
#pragma unroll
        for (int u = 0; u < 8; ++u) {
            unsigned p = bk[i + u];
            a[u] = *(const bf16x8*)(h_bf   + (size_t)(p & 0xFFFFu) * DD + gl * 8);
            r[u] = *(const bf16x8*)(rel_bf + (size_t)(p >> 16)     * DD + gl * 8);
        }
#pragma unroll
        for (int u = 0; u < 8; ++u)
#pragma unroll
            for (int j = 0; j < 8; ++j)
                acc[j] += (float)a[u][j] + (float)r[u][j];
    }
    for (; i + 1 < n; i += 2) {
        unsigned p0 = bk[i], p1 = bk[i + 1];
        bf16x8 a0 = *(const bf16x8*)(h_bf   + (size_t)(p0 & 0xFFFFu) * DD + gl * 8);
        bf16x8 b0 = *(const bf16x8*)(rel_bf + (size_t)(p0 >> 16)     * DD + gl * 8);
        bf16x8 a1 = *(const bf16x8*)(h_bf   + (size_t)(p1 & 0xFFFFu) * DD + gl * 8);
        bf16x8 b1 = *(const bf16x8*)(rel_bf + (size_t)(p1 >> 16)     * DD + gl * 8);
#pragma unroll
        for (int j = 0; j < 8; ++j)
            acc[j] += ((float)a0[j] + (float)b0[j]) + ((float)a1[j] + (float)b1[j]);
    }
    if (i < n) {
        unsigned p0 = bk[i];
        bf16x8 a0 = *(const bf16x8*)(h_bf   + (size_t)(p0 & 0xFFFFu) * DD + gl * 8);
        bf16x8 b0 = *(const bf16x8*)(rel_bf + (size_t)(p0 >> 16)     * DD + gl * 8);
#pragma unroll
        for (int j = 0; j < 8; ++j) acc[j] += (float)a0[j] + (float)b0[j];
    }

    bf16x8 o;
#pragma unroll
    for (int j = 0; j < 8; ++j) o[j] = (__bf16)(acc[j] * sc);
    *(bf16x8*)&As[g * AP + gl * 8] = o;
    *(bf16x8*)&As[g * AP + DD + gl * 8] = own_h;
    __syncthreads();

    // ---- phase 2: MFMA. wave w -> n-tiles 2w, 2w+1 over shared 16 A-rows.
    int lane = tid & 63;
    int wave = tid >> 6;
    int aoff = (lane & 15) * AP + (lane >> 4) * 8;

    f32x4 c0 = (f32x4)0.f, c1 = (f32x4)0.f;
    int nt0 = wave * 2;
#pragma unroll
    for (int kstep = 0; kstep < 8; ++kstep) {
        bf16x8 a = *(const bf16x8*)&As[aoff + kstep * 32];
        const __bf16* bbase = Bp + ((size_t)(kstep * 8 + nt0) * 64 + lane) * 8;
        bf16x8 b0 = *(const bf16x8*)bbase;
        bf16x8 b1 = *(const bf16x8*)(bbase + 64 * 8);
        c0 = __builtin_amdgcn_mfma_f32_16x16x32_bf16(a, b0, c0, 0, 0, 0);
        c1 = __builtin_amdgcn_mfma_f32_16x16x32_bf16(a, b1, c1, 0, 0, 0);
    }

    // epilogue: C/D layout col=lane&15, row=(lane>>4)*4+reg; rows all < NN
    int quad = lane >> 4;
    int col  = lane & 15;
#pragma unroll
    for (int reg = 0; reg < 4; ++reg) {
        float* op = out + (size_t)(row0 + quad * 4 + reg) * DD + col;
        op[nt0 * 16]       = fmaxf(c0[reg], 0.f);
        op[(nt0 + 1) * 16] = fmaxf(c1[reg], 0.f);
    }
}

extern "C" void kernel_launch(void* const* d_in, const int* in_sizes, int n_in,
                              void* d_out, int out_size, void* d_ws, size_t ws_size,
                              hipStream_t stream) {
    const float* h    = (const float*)d_in[0];
    const float* norm = (const float*)d_in[1];
    const float* rel  = (const float*)d_in[2];
    const float* W    = (const float*)d_in[3];
    const float* L    = (const float*)d_in[4];
    const int* esrc   = (const int*)d_in[5];
    const int* edst   = (const int*)d_in[6];
    const int* etyp   = (const int*)d_in[7];
    float* out = (float*)d_out;

    int* ws = (int*)d_ws;
    int* cursor      = ws + OFF_CUR;
    unsigned* bucket = (unsigned*)(ws + OFF_BKT);
    __bf16* h_bf     = (__bf16*)(ws + OFF_HB);
    __bf16* rel_bf   = (__bf16*)(ws + OFF_RELB);
    __bf16* Bp       = (__bf16*)(ws + OFF_BP);

    prep<<<PREP_BLOCKS, 256, 0, stream>>>(h, rel, W, L, h_bf, rel_bf, Bp, cursor);
    fill_bucket<<<(NE / 4 + 255) / 256, 256, 0, stream>>>(esrc, edst, etyp, cursor, bucket);
    fused_gather_mfma<<<NN / 16, 256, 0, stream>>>(h_bf, rel_bf, norm, cursor,
                                                   bucket, Bp, out);
}